// Round 11
// baseline (369.664 us; speedup 1.0000x reference)
//
#include <hip/hip_runtime.h>

// VQ-VAE quantize + EMA update, MI355X.
// R19: (a) scatter+finalize fused WITHOUT cooperative launch: last-64-blocks
//     election (ticket atomicAdd after threadfence; tickets>=192 spin until
//     done==256 then run one finalize slice each). All 256 blocks co-resident
//     (1/CU) => bounded spin. Cross-XCD partials read via agent-scope atomic
//     loads (guards against stale L2 lines cached by the previous graph
//     iteration). done counter zeroed by prep each iteration. Saves one
//     ~25us launch boundary (R14 established ~19-30us/op; others-noise ±20).
//     (b) dist: key = (bits&KMASK)|colu (v_and_or_b32, -1 VALU/state) with
//     TAUK 0.05->0.07 (trunc err <=0.0156 + mfma ~0.01 per value).
//     dist main loop otherwise R18 (linear walk, imm offsets, 4-deep).

#define N_ROWS 131072
#define DIM    64
#define NEMB   1024
#define NRANGE 32
#define KMASK  0xFFFFFC00u
#define TAUK   0.07f

static constexpr float DECAYF = 0.99f;
static constexpr float OMDF   = (float)(1.0 - 0.99);
static constexpr float EPSF   = 1e-5f;
static constexpr float NEPSF  = (float)(1024 * 1e-5);

typedef __attribute__((ext_vector_type(8))) short short8;
typedef __attribute__((ext_vector_type(4))) float f32x4;

static __device__ __forceinline__ unsigned short f2bf(float f) {
    unsigned int u = __builtin_bit_cast(unsigned int, f);
    unsigned int r = (u + 0x7FFFu + ((u >> 16) & 1u)) >> 16;   // RNE
    return (unsigned short)r;
}
static __device__ __forceinline__ float bf2f(unsigned short h) {
    unsigned int u = ((unsigned int)h) << 16;
    return __builtin_bit_cast(float, u);
}
static __device__ __forceinline__ float agent_ld(const float* p) {
    return __hip_atomic_load(p, __ATOMIC_RELAXED, __HIP_MEMORY_SCOPE_AGENT);
}

// ws layout (float offsets)
#define WS_ESUM    0         // 65536 (atomic-fallback target)
#define WS_CNTF    65536     // 1024  (atomic-fallback counts)
#define WS_DIFF    66560     // 1
#define WS_DONE    66561     // 1 (int, election counter)
#define WS_N       66562     // 1 (unused)
#define WS_EE      66564     // 1024
#define WS_EMBEDT  67588     // 65536 (16B aligned)
#define WS_IDX     133124    // 131072 (int)
#define WS_FLAGLST 264196    // 131072 (unused)
#define WS_BFRAG   395268    // 65536 floats = 256 KB (16B aligned)
#define WS_CNTPART 460804    // 32768 (NRANGE x 1024)
#define WS_PART    493572    // NRANGE x 65536 floats (16B aligned)
#define WS_NEED_BYTES ((size_t)(WS_PART + NRANGE * 65536) * 4)

// ---------------- prep: embedT, ee, hi/lo fragments of B' = -2*embed
__global__ void prep_kernel(const float* __restrict__ embed,
                            float* __restrict__ embedT,
                            float* __restrict__ ee,
                            uint4* __restrict__ BfragG,
                            float* __restrict__ ws_diff,
                            int* __restrict__ ws_done) {
    int tid = blockIdx.x * 256 + threadIdx.x;      // 0..16383
    if (tid == 0) { ws_diff[0] = 0.f; ws_done[0] = 0; }
    for (int i = 0; i < 4; ++i) {
        int id = i * 16384 + tid;
        int d = id >> 10, e = id & 1023;
        embedT[e * 64 + d] = embed[id];
    }
    if (tid < NEMB) {
        float s = 0.f;
        for (int d = 0; d < DIM; ++d) {
            float v = embed[d * 1024 + tid];
            s = fmaf(v, v, s);
        }
        ee[tid] = s;
    }
    int fid  = tid >> 6;            // 0..255
    int lane = tid & 63;
    int hl = fid & 1, kt = (fid >> 1) & 1, ct = fid >> 2;
    int col = ct * 16 + (lane & 15);
    int k0  = kt * 32 + (lane >> 4) * 8;
    unsigned short u[8];
    #pragma unroll
    for (int j = 0; j < 8; ++j) {
        float v = -2.0f * embed[(k0 + j) * 1024 + col];
        unsigned short h = f2bf(v);
        if (hl) h = f2bf(v - bf2f(h));
        u[j] = h;
    }
    uint4 wv;
    wv.x = (unsigned)u[0] | ((unsigned)u[1] << 16);
    wv.y = (unsigned)u[2] | ((unsigned)u[3] << 16);
    wv.z = (unsigned)u[4] | ((unsigned)u[5] << 16);
    wv.w = (unsigned)u[6] | ((unsigned)u[7] << 16);
    BfragG[fid * 64 + lane] = wv;
}

// ---------------- dist: hi/lo MFMA + key-argmin + quantize + diff + recheck
__global__ __launch_bounds__(256) void dist_kernel(
        const float* __restrict__ x, const uint4* __restrict__ BfragG,
        const float* __restrict__ ee, const float* __restrict__ embed,
        const float* __restrict__ embedT,
        float* __restrict__ out_q, float* __restrict__ out_ind,
        int* __restrict__ ws_idx, float* __restrict__ ws_diff) {
    __shared__ float sEE[1024];           // 4 KB
    __shared__ int   sIdx[128];
    __shared__ float red[4];
    __shared__ int   sFlagCnt;
    __shared__ int   sFlagRows[128];
    __shared__ float sx[8][64];           // recheck stage
    __shared__ float sff[8];
    __shared__ float sbdw[8][4];
    __shared__ int   sbiw[8][4];
    __shared__ int   schg[8];

    const int t = threadIdx.x;
    const int w = t >> 6, lane = t & 63;
    const int quad = lane >> 4, wl = lane & 15;
    const int rbase = blockIdx.x * 128;

    short8 a_hi[2][2], a_lo[2][2];
    #pragma unroll
    for (int rt = 0; rt < 2; ++rt) {
        int row = rbase + w * 32 + rt * 16 + wl;
        #pragma unroll
        for (int kt = 0; kt < 2; ++kt) {
            const float* px = x + (size_t)row * 64 + kt * 32 + quad * 8;
            float4 v0 = *(const float4*)px;
            float4 v1 = *(const float4*)(px + 4);
            float vv[8] = {v0.x, v0.y, v0.z, v0.w, v1.x, v1.y, v1.z, v1.w};
            short8 ah, al;
            #pragma unroll
            for (int j = 0; j < 8; ++j) {
                unsigned short h = f2bf(vv[j]);
                ah[j] = (short)h;
                al[j] = (short)f2bf(vv[j] - bf2f(h));
            }
            a_hi[rt][kt] = ah; a_lo[rt][kt] = al;
        }
    }

    for (int i = t; i < 1024; i += 256) sEE[i] = ee[i];
    if (t == 0) sFlagCnt = 0;

    float b1[8], b2[8];
    #pragma unroll
    for (int s = 0; s < 8; ++s) { b1[s] = 3.4e38f; b2[s] = 3.4e38f; }

    const f32x4 zacc = {0.f, 0.f, 0.f, 0.f};

    __syncthreads();                      // sEE+sFlagCnt visible

#define GBODY(CB0, CB1, CB2, CB3, COLV)                                        \
    {                                                                          \
        short8 bh0 = __builtin_bit_cast(short8, CB0);                          \
        short8 bl0 = __builtin_bit_cast(short8, CB1);                          \
        short8 bh1 = __builtin_bit_cast(short8, CB2);                          \
        short8 bl1 = __builtin_bit_cast(short8, CB3);                          \
        float eec = sEE[COLV];                                                 \
        unsigned colu = (unsigned)(COLV);                                      \
        _Pragma("unroll")                                                      \
        for (int rt = 0; rt < 2; ++rt) {                                       \
            f32x4 c0 = __builtin_amdgcn_mfma_f32_16x16x32_bf16(a_lo[rt][0], bh0, zacc, 0, 0, 0); \
            f32x4 c1 = __builtin_amdgcn_mfma_f32_16x16x32_bf16(a_lo[rt][1], bh1, zacc, 0, 0, 0); \
            c0 = __builtin_amdgcn_mfma_f32_16x16x32_bf16(a_hi[rt][0], bl0, c0, 0, 0, 0); \
            c1 = __builtin_amdgcn_mfma_f32_16x16x32_bf16(a_hi[rt][1], bl1, c1, 0, 0, 0); \
            c0 = __builtin_amdgcn_mfma_f32_16x16x32_bf16(a_hi[rt][0], bh0, c0, 0, 0, 0); \
            c1 = __builtin_amdgcn_mfma_f32_16x16x32_bf16(a_hi[rt][1], bh1, c1, 0, 0, 0); \
            _Pragma("unroll")                                                  \
            for (int reg = 0; reg < 4; ++reg) {                                \
                float s = c0[reg] + c1[reg] + eec;                             \
                unsigned ku = (__builtin_bit_cast(unsigned, s) & KMASK) | colu;\
                float key = __builtin_bit_cast(float, ku);                     \
                int st = rt * 4 + reg;                                         \
                b2[st] = __builtin_amdgcn_fmed3f(key, b1[st], b2[st]);         \
                b1[st] = fminf(key, b1[st]);                                   \
            }                                                                  \
        }                                                                      \
    }

#define LOADB(S0, S1, S2, S3, P)                                               \
    { const uint4* _p = (P); S0 = _p[0]; S1 = _p[64]; S2 = _p[128]; S3 = _p[192]; }

    // main loop: 64 col-groups of 16 cols; linear walk, 4-deep prefetch.
    {
        const uint4* pa = BfragG + lane;
        uint4 A0, A1, A2, A3, B0, B1, B2, B3;
        uint4 C0, C1, C2, C3, D0, D1, D2, D3;
        LOADB(A0, A1, A2, A3, pa);
        LOADB(B0, B1, B2, B3, pa + 256);
        LOADB(C0, C1, C2, C3, pa + 512);
        LOADB(D0, D1, D2, D3, pa + 768);
        int col = wl;
        for (int it = 0; it < 64; it += 4) {
            GBODY(A0, A1, A2, A3, col);
            if (it + 4 < 64) LOADB(A0, A1, A2, A3, pa + (it + 4) * 256);
            GBODY(B0, B1, B2, B3, col + 16);
            if (it + 5 < 64) LOADB(B0, B1, B2, B3, pa + (it + 5) * 256);
            GBODY(C0, C1, C2, C3, col + 32);
            if (it + 6 < 64) LOADB(C0, C1, C2, C3, pa + (it + 6) * 256);
            GBODY(D0, D1, D2, D3, col + 48);
            if (it + 7 < 64) LOADB(D0, D1, D2, D3, pa + (it + 7) * 256);
            col += 64;
        }
    }
#undef GBODY
#undef LOADB

    // cross-lane reduce over the 16 wl lanes; keys carry the index.
    for (int m = 1; m < 16; m <<= 1) {
        #pragma unroll
        for (int s = 0; s < 8; ++s) {
            float o1 = __shfl_xor(b1[s], m);
            float o2 = __shfl_xor(b2[s], m);
            float mx = fmaxf(b1[s], o1);
            b1[s] = fminf(b1[s], o1);
            b2[s] = fminf(fminf(b2[s], o2), mx);
        }
    }
    if (wl == 0) {
        #pragma unroll
        for (int s = 0; s < 8; ++s) {
            int rt = s >> 2, reg = s & 3;
            int rloc = w * 32 + rt * 16 + quad * 4 + reg;
            int row = rbase + rloc;
            unsigned kb = __builtin_bit_cast(unsigned, b1[s]);
            int col = (int)(kb & 1023u);
            sIdx[rloc] = col;
            ws_idx[row] = col;
            out_ind[row] = (float)col;
            float v1 = __builtin_bit_cast(float, kb & KMASK);
            float v2 = __builtin_bit_cast(float, __builtin_bit_cast(unsigned, b2[s]) & KMASK);
            if (v2 - v1 < TAUK) {
                int p = atomicAdd(&sFlagCnt, 1);
                sFlagRows[p] = rloc;               // p < 128 guaranteed
            }
        }
    }
    __syncthreads();

    // quantize + diff epilogue (old indices; flagged rows fixed below)
    {
        int r = t >> 1, hh = t & 1;
        int e = sIdx[r];
        const float4* et = (const float4*)(embedT + e * 64 + hh * 32);
        const float4* xr = (const float4*)(x + (size_t)(rbase + r) * 64 + hh * 32);
        float4*       qo = (float4*)(out_q + (size_t)(rbase + r) * 64 + hh * 32);
        float dsum = 0.f;
        #pragma unroll
        for (int v = 0; v < 8; ++v) {
            float4 q4 = et[v];
            float4 x4 = xr[v];
            float dx = q4.x - x4.x, dy = q4.y - x4.y, dz = q4.z - x4.z, dw = q4.w - x4.w;
            float4 o;
            o.x = x4.x + dx; o.y = x4.y + dy; o.z = x4.z + dz; o.w = x4.w + dw;
            qo[v] = o;
            dsum += dx * dx + dy * dy + dz * dz + dw * dw;
        }
        for (int o2 = 32; o2 > 0; o2 >>= 1) dsum += __shfl_down(dsum, o2);
        if (lane == 0) red[w] = dsum;
        __syncthreads();
        if (t == 0) atomicAdd(ws_diff, red[0] + red[1] + red[2] + red[3]);
    }

    // fused recheck: exact fp32 re-argmin for flagged rows, batches of 8.
    __syncthreads();                       // quantize stores drained
    int fcnt = sFlagCnt;
    for (int base = 0; base < fcnt; base += 8) {
        int nr = fcnt - base; if (nr > 8) nr = 8;
        __syncthreads();                   // sx reuse guard
        for (int l = t; l < nr * 64; l += 256) {
            int rl = sFlagRows[base + (l >> 6)];
            sx[l >> 6][l & 63] = x[(size_t)(rbase + rl) * 64 + (l & 63)];
        }
        __syncthreads();
        if (t < nr) {
            float ff = 0.f;
            for (int k = 0; k < 64; ++k) ff = fmaf(sx[t][k], sx[t][k], ff);
            sff[t] = ff;
        }
        float acc[8][4];
        #pragma unroll
        for (int r = 0; r < 8; ++r)
            #pragma unroll
            for (int j = 0; j < 4; ++j) acc[r][j] = 0.f;
        int c0i = t * 4;
        for (int k = 0; k < 64; ++k) {
            float4 e4 = *(const float4*)(embed + k * 1024 + c0i);
            #pragma unroll
            for (int r = 0; r < 8; ++r) {
                float xk = sx[r][k];
                acc[r][0] = fmaf(xk, e4.x, acc[r][0]);
                acc[r][1] = fmaf(xk, e4.y, acc[r][1]);
                acc[r][2] = fmaf(xk, e4.z, acc[r][2]);
                acc[r][3] = fmaf(xk, e4.w, acc[r][3]);
            }
        }
        __syncthreads();                   // sff visible
        #pragma unroll
        for (int r = 0; r < 8; ++r) {
            if (r < nr) {
                float ff = sff[r];
                float bd = 3.4e38f; int bi = 0;
                #pragma unroll
                for (int j = 0; j < 4; ++j) {
                    float d = (ff - 2.f * acc[r][j]) + sEE[c0i + j];
                    if (d < bd) { bd = d; bi = c0i + j; }
                }
                for (int m = 32; m > 0; m >>= 1) {
                    float od = __shfl_xor(bd, m);
                    int   oi = __shfl_xor(bi, m);
                    if (od < bd || (od == bd && oi < bi)) { bd = od; bi = oi; }
                }
                if (lane == 0) { sbdw[r][w] = bd; sbiw[r][w] = bi; }
            }
        }
        __syncthreads();
        if (t < nr) {
            float bd = sbdw[t][0]; int bi = sbiw[t][0];
            #pragma unroll
            for (int k2 = 1; k2 < 4; ++k2) {
                float od = sbdw[t][k2]; int oi = sbiw[t][k2];
                if (od < bd || (od == bd && oi < bi)) { bd = od; bi = oi; }
            }
            int rl = sFlagRows[base + t];
            int oi_ = sIdx[rl];
            schg[t] = (bi != oi_) ? bi : -1;
            if (bi != oi_) {
                ws_idx[rbase + rl] = bi;
                out_ind[rbase + rl] = (float)bi;
            }
        }
        __syncthreads();
        for (int r = w; r < nr; r += 4) {
            int ni = schg[r];
            if (ni >= 0) {
                int rl = sFlagRows[base + r];
                int row = rbase + rl;
                int oi_ = sIdx[rl];
                float xv = sx[r][lane];
                float dn   = embedT[ni * 64 + lane] - xv;
                float dold = embedT[oi_ * 64 + lane] - xv;
                out_q[(size_t)row * 64 + lane] = xv + dn;
                float delta = dn * dn - dold * dold;
                for (int o = 32; o > 0; o >>= 1) delta += __shfl_down(delta, o);
                if (lane == 0) atomicAdd(ws_diff, delta);
            }
        }
    }
}

// ---------------- scatter_fin: scatter partials + last-64-block finalize
__global__ __launch_bounds__(1024) void scatter_fin(
        const int* __restrict__ idx, const float* __restrict__ x,
        float* __restrict__ part, float* __restrict__ cntp,
        const float* __restrict__ cluster_size,
        const float* __restrict__ ws_diff,
        const float* __restrict__ embed_avg,
        float* __restrict__ out_diff, float* __restrict__ out_ncs,
        float* __restrict__ out_nea, float* __restrict__ out_ne,
        int* __restrict__ done) {
    __shared__ float shist[8192];         // [1024 codes][8 dims] = 32 KB
    __shared__ float scnt[1024];
    __shared__ float sred[16];
    __shared__ float sn;
    __shared__ int   sTicket;
    const int t = threadIdx.x;
    const int bid = blockIdx.x;
    const int oct = (bid >> 3) & 7;
    const int rb  = (bid & 7) | ((bid >> 6) << 3);
    const int sid = rb * 8 + oct;
    const int w = t >> 6, lane = t & 63;
    const int g = lane >> 3, d = lane & 7;

    for (int i = t; i < 8192; i += 1024) shist[i] = 0.f;
    if (oct == 0) { if (t < 1024) scnt[t] = 0.f; }
    __syncthreads();

    const int row0 = rb * 4096 + w * 256;
    int rcur = row0 + g;
    int e_n = idx[rcur];
    float x_n = x[(size_t)rcur * 64 + oct * 8 + d];
    for (int it = 0; it < 32; ++it) {
        int e = e_n; float xv = x_n;
        int rnext = rcur + 8;
        if (it < 31) {
            e_n = idx[rnext];
            x_n = x[(size_t)rnext * 64 + oct * 8 + d];
        }
        rcur = rnext;
        atomicAdd(&shist[e * 8 + d], xv);
        if (oct == 0 && d == 0) atomicAdd(&scnt[e], 1.0f);
    }
    __syncthreads();

    {
        float* dst = part + (size_t)sid * 8192;
        for (int out = t; out < 8192; out += 1024)
            dst[out] = shist[(out & 1023) * 8 + (out >> 10)];
        if (oct == 0) {
            float* cdst = cntp + rb * 1024;
            if (t < 1024) cdst[t] = scnt[t];
        }
    }

    // election: ticket after device-visible publish of this block's partials
    __threadfence();
    __syncthreads();
    if (t == 0) sTicket = atomicAdd(done, 1);
    __syncthreads();
    int ticket = sTicket;
    if (ticket < 192) return;              // not among the last 64 finishers
    int b = ticket - 192;                  // finalize slice 0..63
    if (t == 0) {
        while (atomicAdd(done, 0) < 256) { }   // all partials published
    }
    __syncthreads();
    __threadfence();

    // finalize slice b: j = b*1024 + t  (agent-scope loads for cross-XCD data)
    {
        float c = 0.f;
        for (int k = 0; k < NRANGE; ++k) c += agent_ld(&cntp[k * 1024 + t]);
        float ncs = DECAYF * cluster_size[t] + OMDF * c;
        float v = ncs;
        for (int o = 32; o > 0; o >>= 1) v += __shfl_down(v, o);
        if ((t & 63) == 0) sred[t >> 6] = v;
        __syncthreads();
        if (t == 0) {
            float n = 0.f;
            for (int i = 0; i < 16; ++i) n += sred[i];
            sn = n;
            if (b == 0) out_diff[0] = ws_diff[0] * (1.0f / 8388608.0f);
        }
        __syncthreads();
        float n = sn;
        if (b == 0) out_ncs[t] = ncs;
        int j = b * 1024 + t;
        float es = 0.f;
        for (int k = 0; k < NRANGE; ++k) es += agent_ld(&part[(size_t)k * 65536 + j]);
        float nea = DECAYF * embed_avg[j] + OMDF * es;
        out_nea[j] = nea;
        float cs = (ncs + EPSF) / (n + NEPSF) * n;
        out_ne[j] = nea / cs;
    }
}

// ---------------- fallback path (atomic scatter + finalize), unchanged R18
__global__ __launch_bounds__(1024) void scatter_kernel(
        const int* __restrict__ idx, const float* __restrict__ x,
        float* __restrict__ esum, float* __restrict__ cntf) {
    __shared__ float shist[8192];
    __shared__ float scnt[1024];
    const int t = threadIdx.x;
    const int bid = blockIdx.x;
    const int oct = (bid >> 3) & 7;
    const int rb  = (bid & 7) | ((bid >> 6) << 3);
    const int w = t >> 6, lane = t & 63;
    const int g = lane >> 3, d = lane & 7;

    for (int i = t; i < 8192; i += 1024) shist[i] = 0.f;
    if (oct == 0) { if (t < 1024) scnt[t] = 0.f; }
    __syncthreads();

    const int row0 = rb * 4096 + w * 256;
    int rcur = row0 + g;
    int e_n = idx[rcur];
    float x_n = x[(size_t)rcur * 64 + oct * 8 + d];
    for (int it = 0; it < 32; ++it) {
        int e = e_n; float xv = x_n;
        int rnext = rcur + 8;
        if (it < 31) {
            e_n = idx[rnext];
            x_n = x[(size_t)rnext * 64 + oct * 8 + d];
        }
        rcur = rnext;
        atomicAdd(&shist[e * 8 + d], xv);
        if (oct == 0 && d == 0) atomicAdd(&scnt[e], 1.0f);
    }
    __syncthreads();

    for (int out = t; out < 8192; out += 1024) {
        float v = shist[(out & 1023) * 8 + (out >> 10)];
        if (v != 0.f)
            atomicAdd(&esum[(oct * 8 + (out >> 10)) * 1024 + (out & 1023)], v);
    }
    if (oct == 0) {
        if (t < 1024) {
            float c = scnt[t];
            if (c != 0.f) atomicAdd(&cntf[t], c);
        }
    }
}

__global__ __launch_bounds__(1024) void finalizeF(
        const float* __restrict__ cluster_size, const float* __restrict__ cntp,
        const float* __restrict__ part, int nrb,
        const float* __restrict__ ws_diff, const float* __restrict__ embed_avg,
        float* __restrict__ out_diff, float* __restrict__ out_ncs,
        float* __restrict__ out_nea, float* __restrict__ out_ne) {
    __shared__ float sred[16];
    __shared__ float sn;
    const int tid = threadIdx.x;
    const int b = blockIdx.x;
    float c = 0.f;
    for (int k = 0; k < nrb; ++k) c += cntp[k * 1024 + tid];
    float ncs = DECAYF * cluster_size[tid] + OMDF * c;
    float v = ncs;
    for (int o = 32; o > 0; o >>= 1) v += __shfl_down(v, o);
    if ((tid & 63) == 0) sred[tid >> 6] = v;
    __syncthreads();
    if (tid == 0) {
        float n = 0.f;
        for (int i = 0; i < 16; ++i) n += sred[i];
        sn = n;
        if (b == 0) out_diff[0] = ws_diff[0] * (1.0f / 8388608.0f);
    }
    __syncthreads();
    float n = sn;
    if (b == 0) out_ncs[tid] = ncs;
    int j = b * 1024 + tid;
    float es = 0.f;
    for (int k = 0; k < nrb; ++k) es += part[(size_t)k * 65536 + j];
    float nea = DECAYF * embed_avg[j] + OMDF * es;
    out_nea[j] = nea;
    float cs = (ncs + EPSF) / (n + NEPSF) * n;
    out_ne[j] = nea / cs;
}

extern "C" void kernel_launch(void* const* d_in, const int* in_sizes, int n_in,
                              void* d_out, int out_size, void* d_ws, size_t ws_size,
                              hipStream_t stream) {
    const float* x            = (const float*)d_in[0];
    const float* embed        = (const float*)d_in[1];
    const float* cluster_size = (const float*)d_in[2];
    const float* embed_avg    = (const float*)d_in[3];

    float* out = (float*)d_out;
    float* out_q    = out;                       // 8388608
    float* out_diff = out + 8388608;             // 1
    float* out_ind  = out + 8388609;             // 131072
    float* out_ncs  = out + 8519681;             // 1024
    float* out_nea  = out + 8520705;             // 65536
    float* out_ne   = out + 8586241;             // 65536

    float* ws = (float*)d_ws;
    float* ws_esum     = ws + WS_ESUM;
    float* ws_cntf     = ws + WS_CNTF;
    float* ws_diff     = ws + WS_DIFF;
    int*   ws_done     = (int*)(ws + WS_DONE);
    float* ws_ee       = ws + WS_EE;
    float* ws_embedT   = ws + WS_EMBEDT;
    int*   ws_idx      = (int*)(ws + WS_IDX);
    uint4* ws_Bfrag    = (uint4*)(ws + WS_BFRAG);
    float* ws_cntpart  = ws + WS_CNTPART;
    float* ws_part     = ws + WS_PART;

    const int use_part = (ws_size >= WS_NEED_BYTES) ? 1 : 0;

    if (!use_part) {
        // atomic fallback needs zeroed esum/cntf (+diff+done)
        hipMemsetAsync(d_ws, 0, (size_t)(WS_DONE + 1) * 4, stream);
    }

    prep_kernel<<<64, 256, 0, stream>>>(embed, ws_embedT, ws_ee, ws_Bfrag,
                                        ws_diff, ws_done);
    dist_kernel<<<N_ROWS / 128, 256, 0, stream>>>(x, ws_Bfrag, ws_ee, embed,
                                                  ws_embedT, out_q, out_ind,
                                                  ws_idx, ws_diff);
    if (use_part) {
        scatter_fin<<<NRANGE * 8, 1024, 0, stream>>>(
            ws_idx, x, ws_part, ws_cntpart, cluster_size, ws_diff, embed_avg,
            out_diff, out_ncs, out_nea, out_ne, ws_done);
    } else {
        scatter_kernel<<<NRANGE * 8, 1024, 0, stream>>>(ws_idx, x, ws_esum, ws_cntf);
        finalizeF<<<64, 1024, 0, stream>>>(cluster_size, ws_cntf, ws_esum, 1,
                                           ws_diff, embed_avg,
                                           out_diff, out_ncs, out_nea, out_ne);
    }
}

// Round 12
// 251.254 us; speedup vs baseline: 1.4713x; 1.4713x over previous
//
#include <hip/hip_runtime.h>

// VQ-VAE quantize + EMA update, MI355X.
// R20: R19's election-spin fusion REVERTED (scatter_fin ran at 205us, ~1%
//     VALU: 64 blocks spinning device-scope RMW on one line + agent-scope
//     loads >> the ~25us launch gap it saved). Launcher = R18's measured
//     4-launch form (247.9us). Kept from R19: dist truncated argmin key
//     ((bits&KMASK)|colu = v_and_or_b32, -1 VALU/state) with TAUK 0.07
//     (trunc err <=0.0156 + mfma ~0.01). New: scatter 2-deep prefetch
//     (R19 profile showed the scatter loop is latency-bound at ~1% VALU).

#define N_ROWS 131072
#define DIM    64
#define NEMB   1024
#define NRANGE 32
#define KMASK  0xFFFFFC00u
#define TAUK   0.07f

static constexpr float DECAYF = 0.99f;
static constexpr float OMDF   = (float)(1.0 - 0.99);
static constexpr float EPSF   = 1e-5f;
static constexpr float NEPSF  = (float)(1024 * 1e-5);

typedef __attribute__((ext_vector_type(8))) short short8;
typedef __attribute__((ext_vector_type(4))) float f32x4;

static __device__ __forceinline__ unsigned short f2bf(float f) {
    unsigned int u = __builtin_bit_cast(unsigned int, f);
    unsigned int r = (u + 0x7FFFu + ((u >> 16) & 1u)) >> 16;   // RNE
    return (unsigned short)r;
}
static __device__ __forceinline__ float bf2f(unsigned short h) {
    unsigned int u = ((unsigned int)h) << 16;
    return __builtin_bit_cast(float, u);
}

// ws layout (float offsets)
#define WS_ESUM    0         // 65536 (atomic-fallback target)
#define WS_CNTF    65536     // 1024  (atomic-fallback counts)
#define WS_DIFF    66560     // 1
#define WS_FLAGCNT 66561     // 1 (unused)
#define WS_N       66562     // 1 (unused)
#define WS_EE      66564     // 1024
#define WS_EMBEDT  67588     // 65536 (16B aligned)
#define WS_IDX     133124    // 131072 (int)
#define WS_FLAGLST 264196    // 131072 (unused)
#define WS_BFRAG   395268    // 65536 floats = 256 KB (16B aligned)
#define WS_CNTPART 460804    // 32768 (NRANGE x 1024)
#define WS_PART    493572    // NRANGE x 65536 floats (16B aligned)
#define WS_NEED_BYTES ((size_t)(WS_PART + NRANGE * 65536) * 4)

// ---------------- prep: embedT, ee, hi/lo fragments of B' = -2*embed
__global__ void prep_kernel(const float* __restrict__ embed,
                            float* __restrict__ embedT,
                            float* __restrict__ ee,
                            uint4* __restrict__ BfragG,
                            float* __restrict__ ws_diff) {
    int tid = blockIdx.x * 256 + threadIdx.x;      // 0..16383
    if (tid == 0) ws_diff[0] = 0.f;
    for (int i = 0; i < 4; ++i) {
        int id = i * 16384 + tid;
        int d = id >> 10, e = id & 1023;
        embedT[e * 64 + d] = embed[id];
    }
    if (tid < NEMB) {
        float s = 0.f;
        for (int d = 0; d < DIM; ++d) {
            float v = embed[d * 1024 + tid];
            s = fmaf(v, v, s);
        }
        ee[tid] = s;
    }
    int fid  = tid >> 6;            // 0..255
    int lane = tid & 63;
    int hl = fid & 1, kt = (fid >> 1) & 1, ct = fid >> 2;
    int col = ct * 16 + (lane & 15);
    int k0  = kt * 32 + (lane >> 4) * 8;
    unsigned short u[8];
    #pragma unroll
    for (int j = 0; j < 8; ++j) {
        float v = -2.0f * embed[(k0 + j) * 1024 + col];
        unsigned short h = f2bf(v);
        if (hl) h = f2bf(v - bf2f(h));
        u[j] = h;
    }
    uint4 wv;
    wv.x = (unsigned)u[0] | ((unsigned)u[1] << 16);
    wv.y = (unsigned)u[2] | ((unsigned)u[3] << 16);
    wv.z = (unsigned)u[4] | ((unsigned)u[5] << 16);
    wv.w = (unsigned)u[6] | ((unsigned)u[7] << 16);
    BfragG[fid * 64 + lane] = wv;
}

// ---------------- dist: hi/lo MFMA + key-argmin + quantize + diff + recheck
__global__ __launch_bounds__(256) void dist_kernel(
        const float* __restrict__ x, const uint4* __restrict__ BfragG,
        const float* __restrict__ ee, const float* __restrict__ embed,
        const float* __restrict__ embedT,
        float* __restrict__ out_q, float* __restrict__ out_ind,
        int* __restrict__ ws_idx, float* __restrict__ ws_diff) {
    __shared__ float sEE[1024];           // 4 KB
    __shared__ int   sIdx[128];
    __shared__ float red[4];
    __shared__ int   sFlagCnt;
    __shared__ int   sFlagRows[128];
    __shared__ float sx[8][64];           // recheck stage
    __shared__ float sff[8];
    __shared__ float sbdw[8][4];
    __shared__ int   sbiw[8][4];
    __shared__ int   schg[8];

    const int t = threadIdx.x;
    const int w = t >> 6, lane = t & 63;
    const int quad = lane >> 4, wl = lane & 15;
    const int rbase = blockIdx.x * 128;

    short8 a_hi[2][2], a_lo[2][2];
    #pragma unroll
    for (int rt = 0; rt < 2; ++rt) {
        int row = rbase + w * 32 + rt * 16 + wl;
        #pragma unroll
        for (int kt = 0; kt < 2; ++kt) {
            const float* px = x + (size_t)row * 64 + kt * 32 + quad * 8;
            float4 v0 = *(const float4*)px;
            float4 v1 = *(const float4*)(px + 4);
            float vv[8] = {v0.x, v0.y, v0.z, v0.w, v1.x, v1.y, v1.z, v1.w};
            short8 ah, al;
            #pragma unroll
            for (int j = 0; j < 8; ++j) {
                unsigned short h = f2bf(vv[j]);
                ah[j] = (short)h;
                al[j] = (short)f2bf(vv[j] - bf2f(h));
            }
            a_hi[rt][kt] = ah; a_lo[rt][kt] = al;
        }
    }

    for (int i = t; i < 1024; i += 256) sEE[i] = ee[i];
    if (t == 0) sFlagCnt = 0;

    float b1[8], b2[8];
    #pragma unroll
    for (int s = 0; s < 8; ++s) { b1[s] = 3.4e38f; b2[s] = 3.4e38f; }

    const f32x4 zacc = {0.f, 0.f, 0.f, 0.f};

    __syncthreads();                      // sEE+sFlagCnt visible

#define GBODY(CB0, CB1, CB2, CB3, COLV)                                        \
    {                                                                          \
        short8 bh0 = __builtin_bit_cast(short8, CB0);                          \
        short8 bl0 = __builtin_bit_cast(short8, CB1);                          \
        short8 bh1 = __builtin_bit_cast(short8, CB2);                          \
        short8 bl1 = __builtin_bit_cast(short8, CB3);                          \
        float eec = sEE[COLV];                                                 \
        unsigned colu = (unsigned)(COLV);                                      \
        _Pragma("unroll")                                                      \
        for (int rt = 0; rt < 2; ++rt) {                                       \
            f32x4 c0 = __builtin_amdgcn_mfma_f32_16x16x32_bf16(a_lo[rt][0], bh0, zacc, 0, 0, 0); \
            f32x4 c1 = __builtin_amdgcn_mfma_f32_16x16x32_bf16(a_lo[rt][1], bh1, zacc, 0, 0, 0); \
            c0 = __builtin_amdgcn_mfma_f32_16x16x32_bf16(a_hi[rt][0], bl0, c0, 0, 0, 0); \
            c1 = __builtin_amdgcn_mfma_f32_16x16x32_bf16(a_hi[rt][1], bl1, c1, 0, 0, 0); \
            c0 = __builtin_amdgcn_mfma_f32_16x16x32_bf16(a_hi[rt][0], bh0, c0, 0, 0, 0); \
            c1 = __builtin_amdgcn_mfma_f32_16x16x32_bf16(a_hi[rt][1], bh1, c1, 0, 0, 0); \
            _Pragma("unroll")                                                  \
            for (int reg = 0; reg < 4; ++reg) {                                \
                float s = c0[reg] + c1[reg] + eec;                             \
                unsigned ku = (__builtin_bit_cast(unsigned, s) & KMASK) | colu;\
                float key = __builtin_bit_cast(float, ku);                     \
                int st = rt * 4 + reg;                                         \
                b2[st] = __builtin_amdgcn_fmed3f(key, b1[st], b2[st]);         \
                b1[st] = fminf(key, b1[st]);                                   \
            }                                                                  \
        }                                                                      \
    }

#define LOADB(S0, S1, S2, S3, P)                                               \
    { const uint4* _p = (P); S0 = _p[0]; S1 = _p[64]; S2 = _p[128]; S3 = _p[192]; }

    // main loop: 64 col-groups of 16 cols; linear walk, 4-deep prefetch.
    {
        const uint4* pa = BfragG + lane;
        uint4 A0, A1, A2, A3, B0, B1, B2, B3;
        uint4 C0, C1, C2, C3, D0, D1, D2, D3;
        LOADB(A0, A1, A2, A3, pa);
        LOADB(B0, B1, B2, B3, pa + 256);
        LOADB(C0, C1, C2, C3, pa + 512);
        LOADB(D0, D1, D2, D3, pa + 768);
        int col = wl;
        for (int it = 0; it < 64; it += 4) {
            GBODY(A0, A1, A2, A3, col);
            if (it + 4 < 64) LOADB(A0, A1, A2, A3, pa + (it + 4) * 256);
            GBODY(B0, B1, B2, B3, col + 16);
            if (it + 5 < 64) LOADB(B0, B1, B2, B3, pa + (it + 5) * 256);
            GBODY(C0, C1, C2, C3, col + 32);
            if (it + 6 < 64) LOADB(C0, C1, C2, C3, pa + (it + 6) * 256);
            GBODY(D0, D1, D2, D3, col + 48);
            if (it + 7 < 64) LOADB(D0, D1, D2, D3, pa + (it + 7) * 256);
            col += 64;
        }
    }
#undef GBODY
#undef LOADB

    // cross-lane reduce over the 16 wl lanes; keys carry the index.
    for (int m = 1; m < 16; m <<= 1) {
        #pragma unroll
        for (int s = 0; s < 8; ++s) {
            float o1 = __shfl_xor(b1[s], m);
            float o2 = __shfl_xor(b2[s], m);
            float mx = fmaxf(b1[s], o1);
            b1[s] = fminf(b1[s], o1);
            b2[s] = fminf(fminf(b2[s], o2), mx);
        }
    }
    if (wl == 0) {
        #pragma unroll
        for (int s = 0; s < 8; ++s) {
            int rt = s >> 2, reg = s & 3;
            int rloc = w * 32 + rt * 16 + quad * 4 + reg;
            int row = rbase + rloc;
            unsigned kb = __builtin_bit_cast(unsigned, b1[s]);
            int col = (int)(kb & 1023u);
            sIdx[rloc] = col;
            ws_idx[row] = col;
            out_ind[row] = (float)col;
            float v1 = __builtin_bit_cast(float, kb & KMASK);
            float v2 = __builtin_bit_cast(float, __builtin_bit_cast(unsigned, b2[s]) & KMASK);
            if (v2 - v1 < TAUK) {
                int p = atomicAdd(&sFlagCnt, 1);
                sFlagRows[p] = rloc;               // p < 128 guaranteed
            }
        }
    }
    __syncthreads();

    // quantize + diff epilogue (old indices; flagged rows fixed below)
    {
        int r = t >> 1, hh = t & 1;
        int e = sIdx[r];
        const float4* et = (const float4*)(embedT + e * 64 + hh * 32);
        const float4* xr = (const float4*)(x + (size_t)(rbase + r) * 64 + hh * 32);
        float4*       qo = (float4*)(out_q + (size_t)(rbase + r) * 64 + hh * 32);
        float dsum = 0.f;
        #pragma unroll
        for (int v = 0; v < 8; ++v) {
            float4 q4 = et[v];
            float4 x4 = xr[v];
            float dx = q4.x - x4.x, dy = q4.y - x4.y, dz = q4.z - x4.z, dw = q4.w - x4.w;
            float4 o;
            o.x = x4.x + dx; o.y = x4.y + dy; o.z = x4.z + dz; o.w = x4.w + dw;
            qo[v] = o;
            dsum += dx * dx + dy * dy + dz * dz + dw * dw;
        }
        for (int o2 = 32; o2 > 0; o2 >>= 1) dsum += __shfl_down(dsum, o2);
        if (lane == 0) red[w] = dsum;
        __syncthreads();
        if (t == 0) atomicAdd(ws_diff, red[0] + red[1] + red[2] + red[3]);
    }

    // fused recheck: exact fp32 re-argmin for flagged rows, batches of 8.
    __syncthreads();                       // quantize stores drained
    int fcnt = sFlagCnt;
    for (int base = 0; base < fcnt; base += 8) {
        int nr = fcnt - base; if (nr > 8) nr = 8;
        __syncthreads();                   // sx reuse guard
        for (int l = t; l < nr * 64; l += 256) {
            int rl = sFlagRows[base + (l >> 6)];
            sx[l >> 6][l & 63] = x[(size_t)(rbase + rl) * 64 + (l & 63)];
        }
        __syncthreads();
        if (t < nr) {
            float ff = 0.f;
            for (int k = 0; k < 64; ++k) ff = fmaf(sx[t][k], sx[t][k], ff);
            sff[t] = ff;
        }
        float acc[8][4];
        #pragma unroll
        for (int r = 0; r < 8; ++r)
            #pragma unroll
            for (int j = 0; j < 4; ++j) acc[r][j] = 0.f;
        int c0i = t * 4;
        for (int k = 0; k < 64; ++k) {
            float4 e4 = *(const float4*)(embed + k * 1024 + c0i);
            #pragma unroll
            for (int r = 0; r < 8; ++r) {
                float xk = sx[r][k];
                acc[r][0] = fmaf(xk, e4.x, acc[r][0]);
                acc[r][1] = fmaf(xk, e4.y, acc[r][1]);
                acc[r][2] = fmaf(xk, e4.z, acc[r][2]);
                acc[r][3] = fmaf(xk, e4.w, acc[r][3]);
            }
        }
        __syncthreads();                   // sff visible
        #pragma unroll
        for (int r = 0; r < 8; ++r) {
            if (r < nr) {
                float ff = sff[r];
                float bd = 3.4e38f; int bi = 0;
                #pragma unroll
                for (int j = 0; j < 4; ++j) {
                    float d = (ff - 2.f * acc[r][j]) + sEE[c0i + j];
                    if (d < bd) { bd = d; bi = c0i + j; }
                }
                for (int m = 32; m > 0; m >>= 1) {
                    float od = __shfl_xor(bd, m);
                    int   oi = __shfl_xor(bi, m);
                    if (od < bd || (od == bd && oi < bi)) { bd = od; bi = oi; }
                }
                if (lane == 0) { sbdw[r][w] = bd; sbiw[r][w] = bi; }
            }
        }
        __syncthreads();
        if (t < nr) {
            float bd = sbdw[t][0]; int bi = sbiw[t][0];
            #pragma unroll
            for (int k2 = 1; k2 < 4; ++k2) {
                float od = sbdw[t][k2]; int oi = sbiw[t][k2];
                if (od < bd || (od == bd && oi < bi)) { bd = od; bi = oi; }
            }
            int rl = sFlagRows[base + t];
            int oi_ = sIdx[rl];
            schg[t] = (bi != oi_) ? bi : -1;
            if (bi != oi_) {
                ws_idx[rbase + rl] = bi;
                out_ind[rbase + rl] = (float)bi;
            }
        }
        __syncthreads();
        for (int r = w; r < nr; r += 4) {
            int ni = schg[r];
            if (ni >= 0) {
                int rl = sFlagRows[base + r];
                int row = rbase + rl;
                int oi_ = sIdx[rl];
                float xv = sx[r][lane];
                float dn   = embedT[ni * 64 + lane] - xv;
                float dold = embedT[oi_ * 64 + lane] - xv;
                out_q[(size_t)row * 64 + lane] = xv + dn;
                float delta = dn * dn - dold * dold;
                for (int o = 32; o > 0; o >>= 1) delta += __shfl_down(delta, o);
                if (lane == 0) atomicAdd(ws_diff, delta);
            }
        }
    }
}

// ---------------- scatter: 32 ranges x 8 dim-octants; 2-deep prefetch (R20)
__global__ __launch_bounds__(1024) void scatter_kernel(
        const int* __restrict__ idx, const float* __restrict__ x,
        float* __restrict__ part_or_esum, float* __restrict__ cntp_or_cntf,
        int use_atomic) {
    __shared__ float shist[8192];         // [1024 codes][8 dims] = 32 KB
    __shared__ float scnt[1024];
    const int t = threadIdx.x;
    const int bid = blockIdx.x;
    const int oct = (bid >> 3) & 7;
    const int rb  = (bid & 7) | ((bid >> 6) << 3);
    const int sid = rb * 8 + oct;
    const int w = t >> 6, lane = t & 63;
    const int g = lane >> 3, d = lane & 7;

    for (int i = t; i < 8192; i += 1024) shist[i] = 0.f;
    if (oct == 0) { if (t < 1024) scnt[t] = 0.f; }
    __syncthreads();

    const int row0 = rb * 4096 + w * 256;
    const int off = oct * 8 + d;
    int rcur = row0 + g;
    int e0 = idx[rcur];
    float x0 = x[(size_t)rcur * 64 + off];
    int e1 = idx[rcur + 8];
    float x1 = x[(size_t)(rcur + 8) * 64 + off];
    for (int it = 0; it < 32; ++it) {                  // 32 x 8 rows per wave
        int e = e0; float xv = x0;
        e0 = e1; x0 = x1;
        int rn = rcur + 16;
        if (it < 30) {                                 // 2-deep prefetch
            e1 = idx[rn];
            x1 = x[(size_t)rn * 64 + off];
        }
        rcur += 8;
        atomicAdd(&shist[e * 8 + d], xv);
        if (oct == 0 && d == 0) atomicAdd(&scnt[e], 1.0f);
    }
    __syncthreads();

    if (!use_atomic) {
        float* dst = part_or_esum + (size_t)sid * 8192;
        for (int out = t; out < 8192; out += 1024)
            dst[out] = shist[(out & 1023) * 8 + (out >> 10)];
        if (oct == 0) {
            float* cdst = cntp_or_cntf + rb * 1024;
            if (t < 1024) cdst[t] = scnt[t];
        }
    } else {
        for (int out = t; out < 8192; out += 1024) {
            float v = shist[(out & 1023) * 8 + (out >> 10)];
            if (v != 0.f)
                atomicAdd(&part_or_esum[(oct * 8 + (out >> 10)) * 1024 + (out & 1023)], v);
        }
        if (oct == 0) {
            if (t < 1024) {
                float c = scnt[t];
                if (c != 0.f) atomicAdd(&cntp_or_cntf[t], c);
            }
        }
    }
}

// ---------------- finalizeF: fused finalize1+finalize2 (64 blocks x 1024)
__global__ __launch_bounds__(1024) void finalizeF(
        const float* __restrict__ cluster_size, const float* __restrict__ cntp,
        const float* __restrict__ part, int nrb,
        const float* __restrict__ ws_diff, const float* __restrict__ embed_avg,
        float* __restrict__ out_diff, float* __restrict__ out_ncs,
        float* __restrict__ out_nea, float* __restrict__ out_ne) {
    __shared__ float sred[16];
    __shared__ float sn;
    const int tid = threadIdx.x;
    const int b = blockIdx.x;
    float c = 0.f;
    for (int k = 0; k < nrb; ++k) c += cntp[k * 1024 + tid];
    float ncs = DECAYF * cluster_size[tid] + OMDF * c;
    float v = ncs;
    for (int o = 32; o > 0; o >>= 1) v += __shfl_down(v, o);
    if ((tid & 63) == 0) sred[tid >> 6] = v;
    __syncthreads();
    if (tid == 0) {
        float n = 0.f;
        for (int i = 0; i < 16; ++i) n += sred[i];
        sn = n;
        if (b == 0) out_diff[0] = ws_diff[0] * (1.0f / 8388608.0f);
    }
    __syncthreads();
    float n = sn;
    if (b == 0) out_ncs[tid] = ncs;
    int j = b * 1024 + tid;                       // dim = b, code = tid
    float es = 0.f;
    for (int k = 0; k < nrb; ++k) es += part[(size_t)k * 65536 + j];
    float nea = DECAYF * embed_avg[j] + OMDF * es;
    out_nea[j] = nea;
    float cs = (ncs + EPSF) / (n + NEPSF) * n;
    out_ne[j] = nea / cs;
}

extern "C" void kernel_launch(void* const* d_in, const int* in_sizes, int n_in,
                              void* d_out, int out_size, void* d_ws, size_t ws_size,
                              hipStream_t stream) {
    const float* x            = (const float*)d_in[0];
    const float* embed        = (const float*)d_in[1];
    const float* cluster_size = (const float*)d_in[2];
    const float* embed_avg    = (const float*)d_in[3];

    float* out = (float*)d_out;
    float* out_q    = out;                       // 8388608
    float* out_diff = out + 8388608;             // 1
    float* out_ind  = out + 8388609;             // 131072
    float* out_ncs  = out + 8519681;             // 1024
    float* out_nea  = out + 8520705;             // 65536
    float* out_ne   = out + 8586241;             // 65536

    float* ws = (float*)d_ws;
    float* ws_esum     = ws + WS_ESUM;
    float* ws_cntf     = ws + WS_CNTF;
    float* ws_diff     = ws + WS_DIFF;
    float* ws_ee       = ws + WS_EE;
    float* ws_embedT   = ws + WS_EMBEDT;
    int*   ws_idx      = (int*)(ws + WS_IDX);
    uint4* ws_Bfrag    = (uint4*)(ws + WS_BFRAG);
    float* ws_cntpart  = ws + WS_CNTPART;
    float* ws_part     = ws + WS_PART;

    const int use_part = (ws_size >= WS_NEED_BYTES) ? 1 : 0;

    if (!use_part) {
        // atomic fallback needs zeroed esum/cntf (+diff)
        hipMemsetAsync(d_ws, 0, (size_t)(WS_FLAGCNT + 1) * 4, stream);
    }

    prep_kernel<<<64, 256, 0, stream>>>(embed, ws_embedT, ws_ee, ws_Bfrag, ws_diff);
    dist_kernel<<<N_ROWS / 128, 256, 0, stream>>>(x, ws_Bfrag, ws_ee, embed,
                                                  ws_embedT, out_q, out_ind,
                                                  ws_idx, ws_diff);
    scatter_kernel<<<NRANGE * 8, 1024, 0, stream>>>(
        ws_idx, x,
        use_part ? ws_part : ws_esum,
        use_part ? ws_cntpart : ws_cntf,
        use_part ? 0 : 1);
    finalizeF<<<64, 1024, 0, stream>>>(cluster_size,
                                       use_part ? ws_cntpart : ws_cntf,
                                       use_part ? ws_part : ws_esum,
                                       use_part ? NRANGE : 1,
                                       ws_diff, embed_avg,
                                       out_diff, out_ncs, out_nea, out_ne);
}

// Round 13
// 249.207 us; speedup vs baseline: 1.4834x; 1.0082x over previous
//
#include <hip/hip_runtime.h>

// VQ-VAE quantize + EMA update, MI355X.
// R21 == R18 verbatim (measured best: 247.9us total, dist 111.1us).
//     Final exploitation round: R20's deltas (truncated key + TAUK 0.07,
//     scatter 2-deep prefetch) measured neutral-to-negative (251.3), so
//     reverted. Session evidence: dist floor ~111us robust across 6
//     structural variants (65% combined pipe util, MFMA-latency-bound at
//     grid-capped occupancy); "others" ~137us dominated by ~19-25us launch
//     boundaries (R14: 7->4 ops paid 56us); both remaining fusion paths
//     failed (coop launch = container-fail; election-spin = +122us, R19).
// Structure: prep (fragments/ee/embedT) -> dist (hi/lo-split bf16 MFMA
//     distance + in-mantissa-key argmin + fused exact recheck of flagged
//     near-ties + quantize/diff) -> scatter (LDS hist partials) ->
//     finalizeF (EMA update + normalize).

#define N_ROWS 131072
#define DIM    64
#define NEMB   1024
#define NRANGE 32
#define KMASK  0xFFFFFC00u
#define TAUK   0.05f

static constexpr float DECAYF = 0.99f;
static constexpr float OMDF   = (float)(1.0 - 0.99);
static constexpr float EPSF   = 1e-5f;
static constexpr float NEPSF  = (float)(1024 * 1e-5);

typedef __attribute__((ext_vector_type(8))) short short8;
typedef __attribute__((ext_vector_type(4))) float f32x4;

static __device__ __forceinline__ unsigned short f2bf(float f) {
    unsigned int u = __builtin_bit_cast(unsigned int, f);
    unsigned int r = (u + 0x7FFFu + ((u >> 16) & 1u)) >> 16;   // RNE
    return (unsigned short)r;
}
static __device__ __forceinline__ float bf2f(unsigned short h) {
    unsigned int u = ((unsigned int)h) << 16;
    return __builtin_bit_cast(float, u);
}

// ws layout (float offsets)
#define WS_ESUM    0         // 65536 (atomic-fallback target)
#define WS_CNTF    65536     // 1024  (atomic-fallback counts)
#define WS_DIFF    66560     // 1
#define WS_FLAGCNT 66561     // 1 (unused)
#define WS_N       66562     // 1 (unused)
#define WS_EE      66564     // 1024
#define WS_EMBEDT  67588     // 65536 (16B aligned)
#define WS_IDX     133124    // 131072 (int)
#define WS_FLAGLST 264196    // 131072 (unused)
#define WS_BFRAG   395268    // 65536 floats = 256 KB (16B aligned)
#define WS_CNTPART 460804    // 32768 (NRANGE x 1024)
#define WS_PART    493572    // NRANGE x 65536 floats (16B aligned)
#define WS_NEED_BYTES ((size_t)(WS_PART + NRANGE * 65536) * 4)

// ---------------- prep: embedT, ee, hi/lo fragments of B' = -2*embed
__global__ void prep_kernel(const float* __restrict__ embed,
                            float* __restrict__ embedT,
                            float* __restrict__ ee,
                            uint4* __restrict__ BfragG,
                            float* __restrict__ ws_diff) {
    int tid = blockIdx.x * 256 + threadIdx.x;      // 0..16383
    if (tid == 0) ws_diff[0] = 0.f;
    for (int i = 0; i < 4; ++i) {
        int id = i * 16384 + tid;
        int d = id >> 10, e = id & 1023;
        embedT[e * 64 + d] = embed[id];
    }
    if (tid < NEMB) {
        float s = 0.f;
        for (int d = 0; d < DIM; ++d) {
            float v = embed[d * 1024 + tid];
            s = fmaf(v, v, s);
        }
        ee[tid] = s;
    }
    int fid  = tid >> 6;            // 0..255
    int lane = tid & 63;
    int hl = fid & 1, kt = (fid >> 1) & 1, ct = fid >> 2;
    int col = ct * 16 + (lane & 15);
    int k0  = kt * 32 + (lane >> 4) * 8;
    unsigned short u[8];
    #pragma unroll
    for (int j = 0; j < 8; ++j) {
        float v = -2.0f * embed[(k0 + j) * 1024 + col];
        unsigned short h = f2bf(v);
        if (hl) h = f2bf(v - bf2f(h));
        u[j] = h;
    }
    uint4 wv;
    wv.x = (unsigned)u[0] | ((unsigned)u[1] << 16);
    wv.y = (unsigned)u[2] | ((unsigned)u[3] << 16);
    wv.z = (unsigned)u[4] | ((unsigned)u[5] << 16);
    wv.w = (unsigned)u[6] | ((unsigned)u[7] << 16);
    BfragG[fid * 64 + lane] = wv;
}

// ---------------- dist: hi/lo MFMA + key-argmin + quantize + diff + recheck
__global__ __launch_bounds__(256) void dist_kernel(
        const float* __restrict__ x, const uint4* __restrict__ BfragG,
        const float* __restrict__ ee, const float* __restrict__ embed,
        const float* __restrict__ embedT,
        float* __restrict__ out_q, float* __restrict__ out_ind,
        int* __restrict__ ws_idx, float* __restrict__ ws_diff) {
    __shared__ float sEE[1024];           // 4 KB
    __shared__ int   sIdx[128];
    __shared__ float red[4];
    __shared__ int   sFlagCnt;
    __shared__ int   sFlagRows[128];
    __shared__ float sx[8][64];           // recheck stage
    __shared__ float sff[8];
    __shared__ float sbdw[8][4];
    __shared__ int   sbiw[8][4];
    __shared__ int   schg[8];

    const int t = threadIdx.x;
    const int w = t >> 6, lane = t & 63;
    const int quad = lane >> 4, wl = lane & 15;
    const int rbase = blockIdx.x * 128;

    short8 a_hi[2][2], a_lo[2][2];
    #pragma unroll
    for (int rt = 0; rt < 2; ++rt) {
        int row = rbase + w * 32 + rt * 16 + wl;
        #pragma unroll
        for (int kt = 0; kt < 2; ++kt) {
            const float* px = x + (size_t)row * 64 + kt * 32 + quad * 8;
            float4 v0 = *(const float4*)px;
            float4 v1 = *(const float4*)(px + 4);
            float vv[8] = {v0.x, v0.y, v0.z, v0.w, v1.x, v1.y, v1.z, v1.w};
            short8 ah, al;
            #pragma unroll
            for (int j = 0; j < 8; ++j) {
                unsigned short h = f2bf(vv[j]);
                ah[j] = (short)h;
                al[j] = (short)f2bf(vv[j] - bf2f(h));
            }
            a_hi[rt][kt] = ah; a_lo[rt][kt] = al;
        }
    }

    for (int i = t; i < 1024; i += 256) sEE[i] = ee[i];
    if (t == 0) sFlagCnt = 0;

    float b1[8], b2[8];
    #pragma unroll
    for (int s = 0; s < 8; ++s) { b1[s] = 3.4e38f; b2[s] = 3.4e38f; }

    const f32x4 zacc = {0.f, 0.f, 0.f, 0.f};

    __syncthreads();                      // sEE+sFlagCnt visible

#define GBODY(CB0, CB1, CB2, CB3, COLV)                                        \
    {                                                                          \
        short8 bh0 = __builtin_bit_cast(short8, CB0);                          \
        short8 bl0 = __builtin_bit_cast(short8, CB1);                          \
        short8 bh1 = __builtin_bit_cast(short8, CB2);                          \
        short8 bl1 = __builtin_bit_cast(short8, CB3);                          \
        float eec = sEE[COLV];                                                 \
        unsigned colu = (unsigned)(COLV);                                      \
        _Pragma("unroll")                                                      \
        for (int rt = 0; rt < 2; ++rt) {                                       \
            f32x4 c0 = __builtin_amdgcn_mfma_f32_16x16x32_bf16(a_lo[rt][0], bh0, zacc, 0, 0, 0); \
            f32x4 c1 = __builtin_amdgcn_mfma_f32_16x16x32_bf16(a_lo[rt][1], bh1, zacc, 0, 0, 0); \
            c0 = __builtin_amdgcn_mfma_f32_16x16x32_bf16(a_hi[rt][0], bl0, c0, 0, 0, 0); \
            c1 = __builtin_amdgcn_mfma_f32_16x16x32_bf16(a_hi[rt][1], bl1, c1, 0, 0, 0); \
            c0 = __builtin_amdgcn_mfma_f32_16x16x32_bf16(a_hi[rt][0], bh0, c0, 0, 0, 0); \
            c1 = __builtin_amdgcn_mfma_f32_16x16x32_bf16(a_hi[rt][1], bh1, c1, 0, 0, 0); \
            _Pragma("unroll")                                                  \
            for (int reg = 0; reg < 4; ++reg) {                                \
                float s = c0[reg] + c1[reg] + eec;                             \
                unsigned ku = ((__builtin_bit_cast(unsigned, s) + 0x200u) & KMASK) | colu; \
                float key = __builtin_bit_cast(float, ku);                     \
                int st = rt * 4 + reg;                                         \
                b2[st] = __builtin_amdgcn_fmed3f(key, b1[st], b2[st]);         \
                b1[st] = fminf(key, b1[st]);                                   \
            }                                                                  \
        }                                                                      \
    }

#define LOADB(S0, S1, S2, S3, P)                                               \
    { const uint4* _p = (P); S0 = _p[0]; S1 = _p[64]; S2 = _p[128]; S3 = _p[192]; }

    // main loop: 64 col-groups of 16 cols; linear walk, 4-deep prefetch.
    {
        const uint4* pa = BfragG + lane;
        uint4 A0, A1, A2, A3, B0, B1, B2, B3;
        uint4 C0, C1, C2, C3, D0, D1, D2, D3;
        LOADB(A0, A1, A2, A3, pa);
        LOADB(B0, B1, B2, B3, pa + 256);
        LOADB(C0, C1, C2, C3, pa + 512);
        LOADB(D0, D1, D2, D3, pa + 768);
        int col = wl;
        for (int it = 0; it < 64; it += 4) {
            GBODY(A0, A1, A2, A3, col);
            if (it + 4 < 64) LOADB(A0, A1, A2, A3, pa + (it + 4) * 256);
            GBODY(B0, B1, B2, B3, col + 16);
            if (it + 5 < 64) LOADB(B0, B1, B2, B3, pa + (it + 5) * 256);
            GBODY(C0, C1, C2, C3, col + 32);
            if (it + 6 < 64) LOADB(C0, C1, C2, C3, pa + (it + 6) * 256);
            GBODY(D0, D1, D2, D3, col + 48);
            if (it + 7 < 64) LOADB(D0, D1, D2, D3, pa + (it + 7) * 256);
            col += 64;
        }
    }
#undef GBODY
#undef LOADB

    // cross-lane reduce over the 16 wl lanes; keys carry the index.
    for (int m = 1; m < 16; m <<= 1) {
        #pragma unroll
        for (int s = 0; s < 8; ++s) {
            float o1 = __shfl_xor(b1[s], m);
            float o2 = __shfl_xor(b2[s], m);
            float mx = fmaxf(b1[s], o1);
            b1[s] = fminf(b1[s], o1);
            b2[s] = fminf(fminf(b2[s], o2), mx);
        }
    }
    if (wl == 0) {
        #pragma unroll
        for (int s = 0; s < 8; ++s) {
            int rt = s >> 2, reg = s & 3;
            int rloc = w * 32 + rt * 16 + quad * 4 + reg;
            int row = rbase + rloc;
            unsigned kb = __builtin_bit_cast(unsigned, b1[s]);
            int col = (int)(kb & 1023u);
            sIdx[rloc] = col;
            ws_idx[row] = col;
            out_ind[row] = (float)col;
            float v1 = __builtin_bit_cast(float, kb & KMASK);
            float v2 = __builtin_bit_cast(float, __builtin_bit_cast(unsigned, b2[s]) & KMASK);
            if (v2 - v1 < TAUK) {
                int p = atomicAdd(&sFlagCnt, 1);
                sFlagRows[p] = rloc;               // p < 128 guaranteed
            }
        }
    }
    __syncthreads();

    // quantize + diff epilogue (old indices; flagged rows fixed below)
    {
        int r = t >> 1, hh = t & 1;
        int e = sIdx[r];
        const float4* et = (const float4*)(embedT + e * 64 + hh * 32);
        const float4* xr = (const float4*)(x + (size_t)(rbase + r) * 64 + hh * 32);
        float4*       qo = (float4*)(out_q + (size_t)(rbase + r) * 64 + hh * 32);
        float dsum = 0.f;
        #pragma unroll
        for (int v = 0; v < 8; ++v) {
            float4 q4 = et[v];
            float4 x4 = xr[v];
            float dx = q4.x - x4.x, dy = q4.y - x4.y, dz = q4.z - x4.z, dw = q4.w - x4.w;
            float4 o;
            o.x = x4.x + dx; o.y = x4.y + dy; o.z = x4.z + dz; o.w = x4.w + dw;
            qo[v] = o;
            dsum += dx * dx + dy * dy + dz * dz + dw * dw;
        }
        for (int o2 = 32; o2 > 0; o2 >>= 1) dsum += __shfl_down(dsum, o2);
        if (lane == 0) red[w] = dsum;
        __syncthreads();
        if (t == 0) atomicAdd(ws_diff, red[0] + red[1] + red[2] + red[3]);
    }

    // fused recheck: exact fp32 re-argmin for flagged rows, batches of 8.
    __syncthreads();                       // quantize stores drained
    int fcnt = sFlagCnt;
    for (int base = 0; base < fcnt; base += 8) {
        int nr = fcnt - base; if (nr > 8) nr = 8;
        __syncthreads();                   // sx reuse guard
        for (int l = t; l < nr * 64; l += 256) {
            int rl = sFlagRows[base + (l >> 6)];
            sx[l >> 6][l & 63] = x[(size_t)(rbase + rl) * 64 + (l & 63)];
        }
        __syncthreads();
        if (t < nr) {
            float ff = 0.f;
            for (int k = 0; k < 64; ++k) ff = fmaf(sx[t][k], sx[t][k], ff);
            sff[t] = ff;
        }
        float acc[8][4];
        #pragma unroll
        for (int r = 0; r < 8; ++r)
            #pragma unroll
            for (int j = 0; j < 4; ++j) acc[r][j] = 0.f;
        int c0i = t * 4;
        for (int k = 0; k < 64; ++k) {
            float4 e4 = *(const float4*)(embed + k * 1024 + c0i);
            #pragma unroll
            for (int r = 0; r < 8; ++r) {
                float xk = sx[r][k];
                acc[r][0] = fmaf(xk, e4.x, acc[r][0]);
                acc[r][1] = fmaf(xk, e4.y, acc[r][1]);
                acc[r][2] = fmaf(xk, e4.z, acc[r][2]);
                acc[r][3] = fmaf(xk, e4.w, acc[r][3]);
            }
        }
        __syncthreads();                   // sff visible
        #pragma unroll
        for (int r = 0; r < 8; ++r) {
            if (r < nr) {
                float ff = sff[r];
                float bd = 3.4e38f; int bi = 0;
                #pragma unroll
                for (int j = 0; j < 4; ++j) {
                    float d = (ff - 2.f * acc[r][j]) + sEE[c0i + j];
                    if (d < bd) { bd = d; bi = c0i + j; }
                }
                for (int m = 32; m > 0; m >>= 1) {
                    float od = __shfl_xor(bd, m);
                    int   oi = __shfl_xor(bi, m);
                    if (od < bd || (od == bd && oi < bi)) { bd = od; bi = oi; }
                }
                if (lane == 0) { sbdw[r][w] = bd; sbiw[r][w] = bi; }
            }
        }
        __syncthreads();
        if (t < nr) {
            float bd = sbdw[t][0]; int bi = sbiw[t][0];
            #pragma unroll
            for (int k2 = 1; k2 < 4; ++k2) {
                float od = sbdw[t][k2]; int oi = sbiw[t][k2];
                if (od < bd || (od == bd && oi < bi)) { bd = od; bi = oi; }
            }
            int rl = sFlagRows[base + t];
            int oi_ = sIdx[rl];
            schg[t] = (bi != oi_) ? bi : -1;
            if (bi != oi_) {
                ws_idx[rbase + rl] = bi;
                out_ind[rbase + rl] = (float)bi;
            }
        }
        __syncthreads();
        for (int r = w; r < nr; r += 4) {
            int ni = schg[r];
            if (ni >= 0) {
                int rl = sFlagRows[base + r];
                int row = rbase + rl;
                int oi_ = sIdx[rl];
                float xv = sx[r][lane];
                float dn   = embedT[ni * 64 + lane] - xv;
                float dold = embedT[oi_ * 64 + lane] - xv;
                out_q[(size_t)row * 64 + lane] = xv + dn;
                float delta = dn * dn - dold * dold;
                for (int o = 32; o > 0; o >>= 1) delta += __shfl_down(delta, o);
                if (lane == 0) atomicAdd(ws_diff, delta);
            }
        }
    }
}

// ---------------- scatter: 32 ranges x 8 dim-octants (R15/R18 form)
__global__ __launch_bounds__(1024) void scatter_kernel(
        const int* __restrict__ idx, const float* __restrict__ x,
        float* __restrict__ part_or_esum, float* __restrict__ cntp_or_cntf,
        int use_atomic) {
    __shared__ float shist[8192];         // [1024 codes][8 dims] = 32 KB
    __shared__ float scnt[1024];
    const int t = threadIdx.x;
    const int bid = blockIdx.x;
    const int oct = (bid >> 3) & 7;
    const int rb  = (bid & 7) | ((bid >> 6) << 3);
    const int sid = rb * 8 + oct;
    const int w = t >> 6, lane = t & 63;
    const int g = lane >> 3, d = lane & 7;

    for (int i = t; i < 8192; i += 1024) shist[i] = 0.f;
    if (oct == 0) { if (t < 1024) scnt[t] = 0.f; }
    __syncthreads();

    const int row0 = rb * 4096 + w * 256;
    int rcur = row0 + g;
    int e_n = idx[rcur];
    float x_n = x[(size_t)rcur * 64 + oct * 8 + d];
    for (int it = 0; it < 32; ++it) {
        int e = e_n; float xv = x_n;
        int rnext = rcur + 8;
        if (it < 31) {
            e_n = idx[rnext];
            x_n = x[(size_t)rnext * 64 + oct * 8 + d];
        }
        rcur = rnext;
        atomicAdd(&shist[e * 8 + d], xv);
        if (oct == 0 && d == 0) atomicAdd(&scnt[e], 1.0f);
    }
    __syncthreads();

    if (!use_atomic) {
        float* dst = part_or_esum + (size_t)sid * 8192;
        for (int out = t; out < 8192; out += 1024)
            dst[out] = shist[(out & 1023) * 8 + (out >> 10)];
        if (oct == 0) {
            float* cdst = cntp_or_cntf + rb * 1024;
            if (t < 1024) cdst[t] = scnt[t];
        }
    } else {
        for (int out = t; out < 8192; out += 1024) {
            float v = shist[(out & 1023) * 8 + (out >> 10)];
            if (v != 0.f)
                atomicAdd(&part_or_esum[(oct * 8 + (out >> 10)) * 1024 + (out & 1023)], v);
        }
        if (oct == 0) {
            if (t < 1024) {
                float c = scnt[t];
                if (c != 0.f) atomicAdd(&cntp_or_cntf[t], c);
            }
        }
    }
}

// ---------------- finalizeF: fused finalize1+finalize2 (64 blocks x 1024)
__global__ __launch_bounds__(1024) void finalizeF(
        const float* __restrict__ cluster_size, const float* __restrict__ cntp,
        const float* __restrict__ part, int nrb,
        const float* __restrict__ ws_diff, const float* __restrict__ embed_avg,
        float* __restrict__ out_diff, float* __restrict__ out_ncs,
        float* __restrict__ out_nea, float* __restrict__ out_ne) {
    __shared__ float sred[16];
    __shared__ float sn;
    const int tid = threadIdx.x;
    const int b = blockIdx.x;
    float c = 0.f;
    for (int k = 0; k < nrb; ++k) c += cntp[k * 1024 + tid];
    float ncs = DECAYF * cluster_size[tid] + OMDF * c;
    float v = ncs;
    for (int o = 32; o > 0; o >>= 1) v += __shfl_down(v, o);
    if ((tid & 63) == 0) sred[tid >> 6] = v;
    __syncthreads();
    if (tid == 0) {
        float n = 0.f;
        for (int i = 0; i < 16; ++i) n += sred[i];
        sn = n;
        if (b == 0) out_diff[0] = ws_diff[0] * (1.0f / 8388608.0f);
    }
    __syncthreads();
    float n = sn;
    if (b == 0) out_ncs[tid] = ncs;
    int j = b * 1024 + tid;                       // dim = b, code = tid
    float es = 0.f;
    for (int k = 0; k < nrb; ++k) es += part[(size_t)k * 65536 + j];
    float nea = DECAYF * embed_avg[j] + OMDF * es;
    out_nea[j] = nea;
    float cs = (ncs + EPSF) / (n + NEPSF) * n;
    out_ne[j] = nea / cs;
}

extern "C" void kernel_launch(void* const* d_in, const int* in_sizes, int n_in,
                              void* d_out, int out_size, void* d_ws, size_t ws_size,
                              hipStream_t stream) {
    const float* x            = (const float*)d_in[0];
    const float* embed        = (const float*)d_in[1];
    const float* cluster_size = (const float*)d_in[2];
    const float* embed_avg    = (const float*)d_in[3];

    float* out = (float*)d_out;
    float* out_q    = out;                       // 8388608
    float* out_diff = out + 8388608;             // 1
    float* out_ind  = out + 8388609;             // 131072
    float* out_ncs  = out + 8519681;             // 1024
    float* out_nea  = out + 8520705;             // 65536
    float* out_ne   = out + 8586241;             // 65536

    float* ws = (float*)d_ws;
    float* ws_esum     = ws + WS_ESUM;
    float* ws_cntf     = ws + WS_CNTF;
    float* ws_diff     = ws + WS_DIFF;
    float* ws_ee       = ws + WS_EE;
    float* ws_embedT   = ws + WS_EMBEDT;
    int*   ws_idx      = (int*)(ws + WS_IDX);
    uint4* ws_Bfrag    = (uint4*)(ws + WS_BFRAG);
    float* ws_cntpart  = ws + WS_CNTPART;
    float* ws_part     = ws + WS_PART;

    const int use_part = (ws_size >= WS_NEED_BYTES) ? 1 : 0;

    if (!use_part) {
        // atomic fallback needs zeroed esum/cntf (+diff)
        hipMemsetAsync(d_ws, 0, (size_t)(WS_FLAGCNT + 1) * 4, stream);
    }

    prep_kernel<<<64, 256, 0, stream>>>(embed, ws_embedT, ws_ee, ws_Bfrag, ws_diff);
    dist_kernel<<<N_ROWS / 128, 256, 0, stream>>>(x, ws_Bfrag, ws_ee, embed,
                                                  ws_embedT, out_q, out_ind,
                                                  ws_idx, ws_diff);
    scatter_kernel<<<NRANGE * 8, 1024, 0, stream>>>(
        ws_idx, x,
        use_part ? ws_part : ws_esum,
        use_part ? ws_cntpart : ws_cntf,
        use_part ? 0 : 1);
    finalizeF<<<64, 1024, 0, stream>>>(cluster_size,
                                       use_part ? ws_cntpart : ws_cntf,
                                       use_part ? ws_part : ws_esum,
                                       use_part ? NRANGE : 1,
                                       ws_diff, embed_avg,
                                       out_diff, out_ncs, out_nea, out_ne);
}